// Round 6
// baseline (52.748 us; speedup 1.0000x reference)
//
#include <hip/hip_runtime.h>
#include <math.h>

#define NKV    8
#define NREP   4
#define NH     32
#define BATCH  8
#define D      128
#define SEQ    4096
#define CHUNKS 32
#define CS     128          // SEQ / CHUNKS
#define HROWS  64           // rows per staged half
#define PSTRIDE 130         // 128 o + m + l per (pair,chunk,rep)

// async global->LDS DMA, 16B per lane, wave-uniform LDS base + lane*16
__device__ __forceinline__ void stage16(const float* src, float* lds_dst) {
    __builtin_amdgcn_global_load_lds(
        (const __attribute__((address_space(1))) void*)src,
        (__attribute__((address_space(3))) void*)lds_dst,
        16, 0, 0);
}

// ---------------------------------------------------------------------------
// Kernel 1: partial attention per (pair = g*8+b, chunk).
// grid (64, CHUNKS), block 256 (4 waves).
// K and V are staged through a 32 KB LDS buffer in 64-row halves via
// global_load_lds (huge MLP, zero VGPR cost). Scores: wave w owns rows
// [w*16, w*16+16) of each half, computes ALL 4 reps (K read once).
// ---------------------------------------------------------------------------
__global__ __launch_bounds__(256, 4) void attn_partial(
    const int*   __restrict__ input_pos,
    const float* __restrict__ q,
    const float* __restrict__ knew,
    const float* __restrict__ vnew,
    const float* __restrict__ kcache,
    const float* __restrict__ vcache,
    const float* __restrict__ mask,
    float*       __restrict__ ws)
{
    const int pair = blockIdx.x;      // g*8 + b
    const int c    = blockIdx.y;
    const int g    = pair >> 3;
    const int b    = pair & 7;
    const int t    = threadIdx.x;
    const int w    = t >> 6;          // wave id
    const int lane = t & 63;
    const int p4   = lane >> 4;       // row within 4-row group (scores)
    const int l16  = lane & 15;       // 8-float segment (scores)
    const int vh   = lane >> 5;       // row parity (staging / PV)
    const int l32  = lane & 31;       // 16B slot within row (staging / PV)
    const int pos  = input_pos[0];

    __shared__ __align__(16) float buf[HROWS * D];   // 32 KB staging
    __shared__ float sc[NREP][CS];                   // scores -> e-values
    __shared__ float ml[NREP][2];                    // per-rep (max, sum)
    float (*opart)[NREP][D] = (float (*)[NREP][D])buf;  // overlay after PV

    const float  scale  = 0.08838834764831845f;   // 1/sqrt(128)
    const size_t kvbase = (size_t)(g * BATCH + b) * SEQ * D;
    const float* kbase  = kcache + kvbase;
    const float* vbase  = vcache + kvbase;
    const float* mrow   = mask + (size_t)pos * SEQ;
    const float* knewr  = knew + (size_t)(g * BATCH + b) * D;
    const float* vnewr  = vnew + (size_t)(g * BATCH + b) * D;
    const int    s0     = c * CS;

    // q fragments for all 4 reps (8 floats each = 32 VGPRs)
    float4 qv[NREP][2];
    #pragma unroll
    for (int r = 0; r < NREP; ++r) {
        const float4* qr = (const float4*)(q + ((size_t)(g * NREP + r) * BATCH + b) * D
                                           + l16 * 8);
        qv[r][0] = qr[0];
        qv[r][1] = qr[1];
    }

    // stage one 64-row half of K or V into buf (8 DMA instrs per wave)
    auto stage_half = [&](const float* base, const float* newrow, int hh) {
        #pragma unroll
        for (int jj = 0; jj < 8; ++jj) {
            const int j  = w * 8 + jj;            // 0..31, wave-uniform
            const int rl = 2 * j + vh;            // local row 0..63 (per-lane)
            const int s  = s0 + hh * HROWS + rl;
            const float* src = ((s == pos) ? newrow : (base + (size_t)s * D)) + l32 * 4;
            stage16(src, &buf[j * 256]);          // 256 floats = 2 rows
        }
    };

    // scores for one half from LDS
    auto scores_half = [&](int hh) {
        #pragma unroll
        for (int i = 0; i < 4; ++i) {
            const int rl = w * 16 + i * 4 + p4;   // 0..63
            const int sl = hh * HROWS + rl;       // 0..127
            const float4* kr = (const float4*)&buf[rl * D + l16 * 8];
            const float4 k0 = kr[0], k1 = kr[1];
            float acc[NREP];
            #pragma unroll
            for (int r = 0; r < NREP; ++r) {
                float a;
                a = k0.x * qv[r][0].x;
                a = fmaf(k0.y, qv[r][0].y, a);
                a = fmaf(k0.z, qv[r][0].z, a);
                a = fmaf(k0.w, qv[r][0].w, a);
                a = fmaf(k1.x, qv[r][1].x, a);
                a = fmaf(k1.y, qv[r][1].y, a);
                a = fmaf(k1.z, qv[r][1].z, a);
                a = fmaf(k1.w, qv[r][1].w, a);
                acc[r] = a;
            }
            #pragma unroll
            for (int off = 1; off < 16; off <<= 1) {
                #pragma unroll
                for (int r = 0; r < NREP; ++r)
                    acc[r] += __shfl_xor(acc[r], off);
            }
            if (l16 == 0) {
                const float mval = mrow[s0 + sl];
                #pragma unroll
                for (int r = 0; r < NREP; ++r)
                    sc[r][sl] = acc[r] * scale + mval;
            }
        }
    };

    // ---- K half 1 ----
    stage_half(kbase, knewr, 0);
    __syncthreads();                  // drain DMA (vmcnt 0) + barrier
    scores_half(0);
    __syncthreads();                  // all waves done reading buf
    // ---- K half 2 ----
    stage_half(kbase, knewr, 1);
    __syncthreads();
    scores_half(1);
    __syncthreads();

    // ---- issue V half 1 now; latency hides under softmax ----
    stage_half(vbase, vnewr, 0);

    // ---- softmax: wave w owns rep r = w ----
    {
        const int r = w;
        float v0 = sc[r][lane];
        float v1 = sc[r][lane + 64];
        float m  = fmaxf(v0, v1);
        #pragma unroll
        for (int off = 1; off < 64; off <<= 1)
            m = fmaxf(m, __shfl_xor(m, off));
        float e0 = __expf(v0 - m);
        float e1 = __expf(v1 - m);
        sc[r][lane]      = e0;
        sc[r][lane + 64] = e1;
        float l = e0 + e1;
        #pragma unroll
        for (int off = 1; off < 64; off <<= 1)
            l += __shfl_xor(l, off);
        if (lane == 0) { ml[r][0] = m; ml[r][1] = l; }
    }
    __syncthreads();                  // V1 ready + e-values visible

    // ---- PV ----
    float4 oacc[NREP];
    #pragma unroll
    for (int r = 0; r < NREP; ++r) oacc[r] = make_float4(0.f, 0.f, 0.f, 0.f);

    auto pv_half = [&](int hh) {
        #pragma unroll
        for (int it = 0; it < 8; ++it) {
            const int rl = w * 16 + it * 2 + vh;
            const int sl = hh * HROWS + rl;
            const float4 v4 = *(const float4*)&buf[rl * D + l32 * 4];
            #pragma unroll
            for (int r = 0; r < NREP; ++r) {
                const float pr = sc[r][sl];
                oacc[r].x = fmaf(pr, v4.x, oacc[r].x);
                oacc[r].y = fmaf(pr, v4.y, oacc[r].y);
                oacc[r].z = fmaf(pr, v4.z, oacc[r].z);
                oacc[r].w = fmaf(pr, v4.w, oacc[r].w);
            }
        }
    };

    pv_half(0);
    __syncthreads();                  // done reading V1
    stage_half(vbase, vnewr, 1);
    __syncthreads();                  // V2 ready
    pv_half(1);

    #pragma unroll
    for (int r = 0; r < NREP; ++r) {
        oacc[r].x += __shfl_xor(oacc[r].x, 32);
        oacc[r].y += __shfl_xor(oacc[r].y, 32);
        oacc[r].z += __shfl_xor(oacc[r].z, 32);
        oacc[r].w += __shfl_xor(oacc[r].w, 32);
    }
    __syncthreads();                  // all waves done reading buf (V2)
    if (vh == 0) {
        #pragma unroll
        for (int r = 0; r < NREP; ++r)
            *(float4*)&opart[w][r][l32 * 4] = oacc[r];   // overlays buf
    }
    __syncthreads();

    // ---- final: sum the 4 wave partials, write workspace ----
    #pragma unroll
    for (int ii = 0; ii < 2; ++ii) {
        int idx = t + ii * 256;       // 0..511 -> (r, d)
        int r   = idx >> 7;
        int d   = idx & 127;
        float sum = opart[0][r][d] + opart[1][r][d]
                  + opart[2][r][d] + opart[3][r][d];
        size_t base = (((size_t)pair * CHUNKS + c) * NREP + r) * PSTRIDE;
        ws[base + d] = sum;
        if (d == 0) { ws[base + 128] = ml[r][0]; ws[base + 129] = ml[r][1]; }
    }
}

// ---------------------------------------------------------------------------
// Kernel 2: LSE-combine the 32 chunks per (pair, rep). grid 256, block 128.
// ---------------------------------------------------------------------------
__global__ __launch_bounds__(128) void attn_reduce(
    const float* __restrict__ ws, float* __restrict__ out)
{
    const int idx  = blockIdx.x;      // (pair, r)
    const int pair = idx >> 2;
    const int r    = idx & 3;
    const int g    = pair >> 3;
    const int b    = pair & 7;
    const int d    = threadIdx.x;

    float mv[CHUNKS], lv[CHUNKS];
    float M = -INFINITY;
    #pragma unroll
    for (int c = 0; c < CHUNKS; ++c) {
        size_t base = (((size_t)pair * CHUNKS + c) * NREP + r) * PSTRIDE;
        float2 t = *(const float2*)&ws[base + 128];
        mv[c] = t.x; lv[c] = t.y;
        M = fmaxf(M, t.x);
    }
    float acc = 0.f, L = 0.f;
    #pragma unroll
    for (int c = 0; c < CHUNKS; ++c) {
        size_t base = (((size_t)pair * CHUNKS + c) * NREP + r) * PSTRIDE;
        float wgt = __expf(mv[c] - M);
        acc += ws[base + d] * wgt;
        L   += lv[c] * wgt;
    }
    int h = g * NREP + r;
    out[(size_t)b * (NH * D) + h * D + d] = acc / L;
}

// ---------------------------------------------------------------------------
// Fallback (ws too small): one block per (head, batch), full sequence.
// grid 256, block 256.
// ---------------------------------------------------------------------------
__global__ __launch_bounds__(256) void attn_full(
    const int*   __restrict__ input_pos,
    const float* __restrict__ q,
    const float* __restrict__ knew,
    const float* __restrict__ vnew,
    const float* __restrict__ kcache,
    const float* __restrict__ vcache,
    const float* __restrict__ mask,
    float*       __restrict__ out)
{
    const int idx = blockIdx.x;       // h*8 + b
    const int h   = idx >> 3;
    const int b   = idx & 7;
    const int g   = h >> 2;
    const int t   = threadIdx.x;
    const int wave = t >> 6, lane = t & 63, half = lane >> 5, l32 = lane & 31;
    const int pos = input_pos[0];

    __shared__ float sc[SEQ];         // 16 KB
    __shared__ float wred[4];
    __shared__ float oacc[2][D];

    const size_t kvbase = (size_t)(g * BATCH + b) * SEQ * D;
    const float* kbase  = kcache + kvbase;
    const float* vbase  = vcache + kvbase;
    const float* mrow   = mask + (size_t)pos * SEQ;
    const float* knewr  = knew + (size_t)(g * BATCH + b) * D;
    const float* vnewr  = vnew + (size_t)(g * BATCH + b) * D;
    const float  scale  = 0.08838834764831845f;

    float4 qv = ((const float4*)(q + (size_t)(h * BATCH + b) * D))[l32];

    for (int p = 0; p < SEQ / 8; ++p) {
        int s = p * 8 + wave * 2 + half;
        const float4* krow = (s == pos) ? (const float4*)knewr
                                        : (const float4*)(kbase + (size_t)s * D);
        float4 kv = krow[l32];
        float acc = qv.x * kv.x + qv.y * kv.y + qv.z * kv.z + qv.w * kv.w;
        #pragma unroll
        for (int off = 1; off < 32; off <<= 1)
            acc += __shfl_xor(acc, off);
        if (l32 == 0) sc[s] = acc * scale + mrow[s];
    }
    __syncthreads();

    float m = -INFINITY;
    for (int s = t; s < SEQ; s += 256) m = fmaxf(m, sc[s]);
    #pragma unroll
    for (int off = 1; off < 64; off <<= 1) m = fmaxf(m, __shfl_xor(m, off));
    if (lane == 0) wred[wave] = m;
    __syncthreads();
    m = fmaxf(fmaxf(wred[0], wred[1]), fmaxf(wred[2], wred[3]));
    __syncthreads();

    float l = 0.f;
    for (int s = t; s < SEQ; s += 256) { float e = __expf(sc[s] - m); sc[s] = e; l += e; }
    #pragma unroll
    for (int off = 1; off < 64; off <<= 1) l += __shfl_xor(l, off);
    __syncthreads();
    if (lane == 0) wred[wave] = l;
    __syncthreads();
    float L = wred[0] + wred[1] + wred[2] + wred[3];

    {
        int hf = t >> 7, d = t & 127;
        float acc = 0.f;
        for (int s = hf * (SEQ / 2); s < (hf + 1) * (SEQ / 2); ++s) {
            const float* vrow = (s == pos) ? vnewr : (vbase + (size_t)s * D);
            acc += sc[s] * vrow[d];
        }
        oacc[hf][d] = acc;
    }
    __syncthreads();
    if (t < D) out[(size_t)b * (NH * D) + h * D + t] = (oacc[0][t] + oacc[1][t]) / L;
}

extern "C" void kernel_launch(void* const* d_in, const int* in_sizes, int n_in,
                              void* d_out, int out_size, void* d_ws, size_t ws_size,
                              hipStream_t stream) {
    const int*   input_pos = (const int*)  d_in[0];
    const float* q         = (const float*)d_in[1];
    const float* k         = (const float*)d_in[2];
    const float* v         = (const float*)d_in[3];
    const float* kcache    = (const float*)d_in[4];
    const float* vcache    = (const float*)d_in[5];
    const float* mask      = (const float*)d_in[6];
    float* out = (float*)d_out;

    const size_t need = (size_t)64 * CHUNKS * NREP * PSTRIDE * sizeof(float);
    if (ws_size >= need) {
        dim3 g1(64, CHUNKS);
        attn_partial<<<g1, 256, 0, stream>>>(input_pos, q, k, v, kcache, vcache, mask,
                                             (float*)d_ws);
        attn_reduce<<<256, 128, 0, stream>>>((const float*)d_ws, out);
    } else {
        attn_full<<<256, 256, 0, stream>>>(input_pos, q, k, v, kcache, vcache, mask, out);
    }
}